// Round 2
// baseline (701.013 us; speedup 1.0000x reference)
//
#include <hip/hip_runtime.h>

#define B_ 16
#define CCH 128
#define NPIX 16384
#define NH 4
#define DH 32
#define NCHUNK 1024
#define NTILES 16   // NCHUNK/64
#define NCHUNKS 16  // NPIX/NCHUNK
#define SCALE 0.17677669529663687f  // 32^-0.5

// ws layout (floats):
//   ctx_part: [B][NH][NCHUNKS][32][32] = 1,048,576 floats
//   z_part:   [B][NH][NCHUNKS][32]     =    32,768 floats
//   P:        [B][128][128]            =   262,144 floats
#define CTXP_OFF 0
#define ZP_OFF   1048576
#define P_OFF    1081344

// Kernel A: fused KV 1x1-conv + exp + context accumulation.
// One workgroup per (b, h, chunk of 1024 columns). Computes the 64 KV rows
// for this head over its columns tile-by-tile (64 cols), exponentiates K,
// accumulates ctx[d][e] += exp(K[d,n]) * V[e,n] and Z[d] += exp(K[d,n]).
__global__ __launch_bounds__(256, 2) void ctx_kernel(
    const float* __restrict__ x, const float* __restrict__ w_qkv,
    float* __restrict__ ctx_part, float* __restrict__ z_part)
{
  const int chunk = blockIdx.x, h = blockIdx.y, b = blockIdx.z;
  const int t = threadIdx.x;
  __shared__ float Wt[128][64];   // Wt[k][r]: r<32 -> K row h*32+r, r>=32 -> V row
  __shared__ float U[8192];       // 32KB union: Xs[128][64] | {Te[32][65], Tv[64][36]} | zbuf
  float (*Xs)[64] = (float(*)[64])U;
  float (*Te)[65] = (float(*)[65])U;             // exp(K) tile, padded stride 65
  float (*Tv)[36] = (float(*)[36])(U + 2080);    // V^T tile: Tv[col][e], stride 36 (f4-aligned)

  // Load W for this head, transposed: Wt[k][r]
  {
    const int r  = t >> 2;
    const int k0 = (t & 3) * 32;
    const int grow = (r < DH) ? (128 + h * DH + r) : (256 + h * DH + (r - DH));
    const float* src = w_qkv + grow * CCH + k0;
#pragma unroll
    for (int i = 0; i < 32; i += 4) {
      const float4 v = *(const float4*)(src + i);
      Wt[k0 + i + 0][r] = v.x;
      Wt[k0 + i + 1][r] = v.y;
      Wt[k0 + i + 2][r] = v.z;
      Wt[k0 + i + 3][r] = v.w;
    }
  }

  const int tx = t & 15, ty = t >> 4;
  const int r4 = ty * 4, c4 = tx * 4;        // GEMM output mapping: rows r4..r4+3, cols c4..c4+3
  const int d_ctx = t >> 3, e0 = (t & 7) * 4; // ctx mapping: d, e0..e0+3
  const int cr = t >> 4, cj = (t & 15) * 4;   // Xs load mapping

  float cacc[4]  = {0.f, 0.f, 0.f, 0.f};
  float zpart[4] = {0.f, 0.f, 0.f, 0.f};
  const float* xb = x + (size_t)b * CCH * NPIX;

  for (int tile = 0; tile < NTILES; ++tile) {
    const int n0 = chunk * NCHUNK + tile * 64;
    __syncthreads();  // previous readers of U done
    // stage x tile [128][64]
#pragma unroll
    for (int i = 0; i < 8; ++i) {
      const float4 v = *(const float4*)(xb + (size_t)(cr + i * 16) * NPIX + n0 + cj);
      *(float4*)&Xs[cr + i * 16][cj] = v;
    }
    __syncthreads();

    // 64x64 KV tile GEMM, K=128
    float acc[4][4];
#pragma unroll
    for (int ii = 0; ii < 4; ++ii)
#pragma unroll
      for (int jj = 0; jj < 4; ++jj) acc[ii][jj] = 0.f;
#pragma unroll 4
    for (int k = 0; k < 128; ++k) {
      const float4 wv = *(const float4*)&Wt[k][r4];
      const float4 xv = *(const float4*)&Xs[k][c4];
      acc[0][0] += wv.x * xv.x; acc[0][1] += wv.x * xv.y; acc[0][2] += wv.x * xv.z; acc[0][3] += wv.x * xv.w;
      acc[1][0] += wv.y * xv.x; acc[1][1] += wv.y * xv.y; acc[1][2] += wv.y * xv.z; acc[1][3] += wv.y * xv.w;
      acc[2][0] += wv.z * xv.x; acc[2][1] += wv.z * xv.y; acc[2][2] += wv.z * xv.z; acc[2][3] += wv.z * xv.w;
      acc[3][0] += wv.w * xv.x; acc[3][1] += wv.w * xv.y; acc[3][2] += wv.w * xv.z; acc[3][3] += wv.w * xv.w;
    }
    __syncthreads();  // Xs readers done before overwriting U with Te/Tv

    if (ty < 8) {     // K rows: exponentiate, accumulate Z
#pragma unroll
      for (int ii = 0; ii < 4; ++ii) {
        const float ea = __expf(acc[ii][0]);
        const float eb = __expf(acc[ii][1]);
        const float ec = __expf(acc[ii][2]);
        const float ed = __expf(acc[ii][3]);
        Te[r4 + ii][c4 + 0] = ea;
        Te[r4 + ii][c4 + 1] = eb;
        Te[r4 + ii][c4 + 2] = ec;
        Te[r4 + ii][c4 + 3] = ed;
        zpart[ii] += ea + eb + ec + ed;
      }
    } else {          // V rows: store transposed
#pragma unroll
      for (int ii = 0; ii < 4; ++ii)
#pragma unroll
        for (int jj = 0; jj < 4; ++jj)
          Tv[c4 + jj][r4 - 32 + ii] = acc[ii][jj];
    }
    __syncthreads();

    // ctx accumulation: cacc[e] += exp(K[d][col]) * V[e][col]
#pragma unroll 4
    for (int col = 0; col < 64; ++col) {
      const float ek = Te[d_ctx][col];
      const float4 vv = *(const float4*)&Tv[col][e0];
      cacc[0] += ek * vv.x;
      cacc[1] += ek * vv.y;
      cacc[2] += ek * vv.z;
      cacc[3] += ek * vv.w;
    }
  }

  // write ctx partials (deterministic, no atomics)
  {
    const size_t base = (((size_t)(b * NH + h) * NCHUNKS + chunk) * 1024) + (size_t)d_ctx * 32 + e0;
    *(float4*)&ctx_part[base] = make_float4(cacc[0], cacc[1], cacc[2], cacc[3]);
  }

  // Z reduction across the 16 tx threads per row
  __syncthreads();
  float (*zbuf)[17] = (float(*)[17])U;
  if (ty < 8) {
#pragma unroll
    for (int ii = 0; ii < 4; ++ii) zbuf[r4 + ii][tx] = zpart[ii];
  }
  __syncthreads();
  if (t < 32) {
    float s = 0.f;
#pragma unroll
    for (int j = 0; j < 16; ++j) s += zbuf[t][j];
    z_part[((size_t)(b * NH + h) * NCHUNKS + chunk) * 32 + t] = s;
  }
}

// Kernel B: reduce chunk partials, normalize context, fold everything into
// P_b = SCALE * (W_out · ctx_b) · W_q   (one 128x128 matrix per batch)
__global__ __launch_bounds__(256, 1) void makeP(
    const float* __restrict__ ctx_part, const float* __restrict__ z_part,
    const float* __restrict__ w_out, const float* __restrict__ w_qkv,
    float* __restrict__ P)
{
  const int b = blockIdx.x, t = threadIdx.x;
  __shared__ float ctxn[4096];   // [hd][e] = ctx[h][d][e]/Z[h][d]
  __shared__ float zs[128];
  __shared__ float M[128][128];  // M[o][hd] = sum_e w_out[o][h*32+e]*ctxn[hd][e]

  if (t < 128) {
    float s = 0.f;
    for (int ch = 0; ch < NCHUNKS; ++ch)
      s += z_part[((size_t)(b * NH + (t >> 5)) * NCHUNKS + ch) * 32 + (t & 31)];
    zs[t] = s;
  }
  __syncthreads();
  for (int i = t; i < 4096; i += 256) {
    const int h = i >> 10;
    float s = 0.f;
    for (int ch = 0; ch < NCHUNKS; ++ch)
      s += ctx_part[((size_t)(b * NH + h) * NCHUNKS + ch) * 1024 + (i & 1023)];
    ctxn[i] = s / zs[i >> 5];
  }
  __syncthreads();
  {
    const int o = t >> 1;
    for (int j = 0; j < 64; ++j) {
      const int hd = (t & 1) * 64 + j;
      const int h = hd >> 5;
      float s = 0.f;
#pragma unroll 8
      for (int e = 0; e < 32; ++e)
        s += w_out[o * CCH + h * DH + e] * ctxn[(hd << 5) + e];
      M[o][hd] = s;
    }
  }
  __syncthreads();
  {
    const int o = t >> 1;
    for (int j = 0; j < 64; ++j) {
      const int c = (t & 1) * 64 + j;
      float s = 0.f;
#pragma unroll 8
      for (int hd = 0; hd < 128; ++hd)
        s += M[o][hd] * w_qkv[hd * CCH + c];
      P[((size_t)b * CCH + o) * CCH + c] = s * SCALE;
    }
  }
}

// Kernel C: y[b] = P_b · x[b] + b_out
__global__ __launch_bounds__(256, 2) void out_gemm(
    const float* __restrict__ x, const float* __restrict__ P,
    const float* __restrict__ bias, float* __restrict__ y)
{
  const int nt = blockIdx.x, rb = blockIdx.y, b = blockIdx.z;
  const int t = threadIdx.x;
  __shared__ float Pt[128][64];
  __shared__ float Xs[128][64];
  {
    const int r = t >> 2, k0 = (t & 3) * 32;
    const float* src = P + ((size_t)b * CCH + rb * 64 + r) * CCH + k0;
#pragma unroll
    for (int i = 0; i < 32; i += 4) {
      const float4 v = *(const float4*)(src + i);
      Pt[k0 + i + 0][r] = v.x;
      Pt[k0 + i + 1][r] = v.y;
      Pt[k0 + i + 2][r] = v.z;
      Pt[k0 + i + 3][r] = v.w;
    }
  }
  const int tx = t & 15, ty = t >> 4;
  const int r4 = ty * 4, c4 = tx * 4;
  const float* xb = x + (size_t)b * CCH * NPIX + nt * 64;
  {
    const int cr = t >> 4, cj = (t & 15) * 4;
#pragma unroll
    for (int i = 0; i < 8; ++i)
      *(float4*)&Xs[cr + i * 16][cj] = *(const float4*)(xb + (size_t)(cr + i * 16) * NPIX + cj);
  }
  __syncthreads();
  float acc[4][4];
#pragma unroll
  for (int ii = 0; ii < 4; ++ii)
#pragma unroll
    for (int jj = 0; jj < 4; ++jj) acc[ii][jj] = 0.f;
#pragma unroll 4
  for (int k = 0; k < 128; ++k) {
    const float4 wv = *(const float4*)&Pt[k][r4];
    const float4 xv = *(const float4*)&Xs[k][c4];
    acc[0][0] += wv.x * xv.x; acc[0][1] += wv.x * xv.y; acc[0][2] += wv.x * xv.z; acc[0][3] += wv.x * xv.w;
    acc[1][0] += wv.y * xv.x; acc[1][1] += wv.y * xv.y; acc[1][2] += wv.y * xv.z; acc[1][3] += wv.y * xv.w;
    acc[2][0] += wv.z * xv.x; acc[2][1] += wv.z * xv.y; acc[2][2] += wv.z * xv.z; acc[2][3] += wv.z * xv.w;
    acc[3][0] += wv.w * xv.x; acc[3][1] += wv.w * xv.y; acc[3][2] += wv.w * xv.z; acc[3][3] += wv.w * xv.w;
  }
  float* yb = y + ((size_t)b * CCH + rb * 64) * NPIX + nt * 64;
#pragma unroll
  for (int ii = 0; ii < 4; ++ii) {
    const float bv = bias[rb * 64 + r4 + ii];
    float4 o;
    o.x = acc[ii][0] + bv;
    o.y = acc[ii][1] + bv;
    o.z = acc[ii][2] + bv;
    o.w = acc[ii][3] + bv;
    *(float4*)(yb + (size_t)(r4 + ii) * NPIX + c4) = o;
  }
}

extern "C" void kernel_launch(void* const* d_in, const int* in_sizes, int n_in,
                              void* d_out, int out_size, void* d_ws, size_t ws_size,
                              hipStream_t stream) {
  const float* x     = (const float*)d_in[0];
  const float* w_qkv = (const float*)d_in[1];
  const float* w_out = (const float*)d_in[2];
  const float* b_out = (const float*)d_in[3];
  float* ws = (float*)d_ws;
  float* ctx_part = ws + CTXP_OFF;
  float* z_part   = ws + ZP_OFF;
  float* P        = ws + P_OFF;
  float* y = (float*)d_out;

  ctx_kernel<<<dim3(NCHUNKS, NH, B_), 256, 0, stream>>>(x, w_qkv, ctx_part, z_part);
  makeP<<<dim3(B_), 256, 0, stream>>>(ctx_part, z_part, w_out, w_qkv, P);
  out_gemm<<<dim3(NPIX / 64, 2, B_), 256, 0, stream>>>(x, P, b_out, y);
}

// Round 4
// 377.949 us; speedup vs baseline: 1.8548x; 1.8548x over previous
//
#include <hip/hip_runtime.h>

typedef float f4 __attribute__((ext_vector_type(4)));
typedef short s4 __attribute__((ext_vector_type(4)));
typedef short s8 __attribute__((ext_vector_type(8)));
typedef unsigned int u32;

#define SCALE 0.17677669529663687f

static __device__ __forceinline__ short bf16c(float f) {
  u32 u = __builtin_bit_cast(u32, f);
  u32 r = u + 0x7fffu + ((u >> 16) & 1u);
  return (short)(r >> 16);
}

static __device__ __forceinline__ f4 mfma32(s8 a, s8 b, f4 c) {
  return __builtin_amdgcn_mfma_f32_16x16x32_bf16(a, b, c, 0, 0, 0);
}
// Zero-padded effective K=16. Slots j=0..3 of A pair with slots j=0..3 of B:
// both operands use the m92-verified contiguous mapping k=(l>>4)*8+j, so
// slot j of A and slot j of B contract at the same k.
static __device__ __forceinline__ f4 bmm16(s4 a, s4 b, f4 c) {
  s8 A = {a[0], a[1], a[2], a[3], (short)0, (short)0, (short)0, (short)0};
  s8 B = {b[0], b[1], b[2], b[3], (short)0, (short)0, (short)0, (short)0};
  return __builtin_amdgcn_mfma_f32_16x16x32_bf16(A, B, c, 0, 0, 0);
}

#define XSTRIDE 280  // bytes per x^T row in LDS: 128 bf16 = 256B + 24B pad

// ---------------------------------------------------------------------------
// Kernel A: fused KV 1x1-conv (MFMA) + exp + ctx accumulation.
// Grid (16 chunks of 1024 n, 16 b); 256 thr = 4 waves = 4 heads.
// Per 64n tile: stage x^T (in-register 4x4 transpose -> padded LDS),
// D[n][kv] = x^T · W^T via verified contiguous-K frags, exp(K-part) and
// V-part chain in-register into the ctx MFMA (zero-padded K=16).
// ---------------------------------------------------------------------------
__global__ __launch_bounds__(256) void ctx_kernel(
    const float* __restrict__ x, const float* __restrict__ wqkv,
    float* __restrict__ cp, float* __restrict__ zp)
{
  const int chunk = blockIdx.x, b = blockIdx.y;
  const int tid = threadIdx.x, lane = tid & 63, h = tid >> 6;
  __shared__ __align__(16) char lds[2 * 64 * XSTRIDE];  // 35840 B

  // Resident W^T B-frags: wf[s][kc]; s=0,1 -> K rows, s=2,3 -> V rows.
  s8 wf[4][4];
  {
    const int colr = lane & 15, g = lane >> 4;
#pragma unroll
    for (int s = 0; s < 4; ++s) {
      const int grow = (s < 2 ? 128 : 256) + h * 32 + (s & 1) * 16 + colr;
#pragma unroll
      for (int kc = 0; kc < 4; ++kc) {
        const float* src = wqkv + grow * 128 + kc * 32 + g * 8;
        const f4 a = *(const f4*)src;
        const f4 c2 = *(const f4*)(src + 4);
        s8 t = {bf16c(a[0]), bf16c(a[1]), bf16c(a[2]), bf16c(a[3]),
                bf16c(c2[0]), bf16c(c2[1]), bf16c(c2[2]), bf16c(c2[3])};
        wf[s][kc] = t;
      }
    }
  }

  f4 ctxacc[2][2];
#pragma unroll
  for (int a = 0; a < 2; ++a)
#pragma unroll
    for (int e2 = 0; e2 < 2; ++e2) ctxacc[a][e2] = (f4){0.f, 0.f, 0.f, 0.f};
  float zloc[2] = {0.f, 0.f};

  const float* xb = x + (size_t)b * 128 * 16384 + chunk * 1024;
  const int nq = tid & 15, ch = tid >> 4;  // staging map: n-quad, c-quad
  f4 v[2][4];

  auto aload = [&](int tl) {
#pragma unroll
    for (int q = 0; q < 2; ++q) {
      const int c0 = ch * 4 + q * 64;
#pragma unroll
      for (int i = 0; i < 4; ++i)
        v[q][i] = *(const f4*)(xb + (size_t)(c0 + i) * 16384 + tl * 64 + nq * 4);
    }
  };
  auto awrite = [&](int buf) {
#pragma unroll
    for (int q = 0; q < 2; ++q) {
      const int c0 = ch * 4 + q * 64;
#pragma unroll
      for (int j = 0; j < 4; ++j) {
        s4 t = {bf16c(v[q][0][j]), bf16c(v[q][1][j]), bf16c(v[q][2][j]),
                bf16c(v[q][3][j])};
        *(s4*)(lds + buf * (64 * XSTRIDE) + (nq * 4 + j) * XSTRIDE + c0 * 2) = t;
      }
    }
  };
  auto compute = [&](int buf) {
#pragma unroll
    for (int nt = 0; nt < 4; ++nt) {
      const char* rp =
          lds + buf * (64 * XSTRIDE) + (nt * 16 + (lane & 15)) * XSTRIDE +
          (lane >> 4) * 16;
      s8 af[4];
#pragma unroll
      for (int kc = 0; kc < 4; ++kc) {
        const s4 lo = *(const s4*)(rp + kc * 64);
        const s4 hi = *(const s4*)(rp + kc * 64 + 8);
        af[kc] = __builtin_shufflevector(lo, hi, 0, 1, 2, 3, 4, 5, 6, 7);
      }
      f4 acc[4];
#pragma unroll
      for (int s = 0; s < 4; ++s) acc[s] = (f4){0.f, 0.f, 0.f, 0.f};
#pragma unroll
      for (int kc = 0; kc < 4; ++kc)
#pragma unroll
        for (int s = 0; s < 4; ++s)
          acc[s] = mfma32(af[kc], wf[s][kc], acc[s]);
      // exp on K-tiles; chain into ctx MFMA (slot j=r <-> n = 4g + r).
      f4 e0, e1;
#pragma unroll
      for (int r = 0; r < 4; ++r) {
        e0[r] = __expf(acc[0][r]);
        e1[r] = __expf(acc[1][r]);
      }
      zloc[0] += e0[0] + e0[1] + e0[2] + e0[3];
      zloc[1] += e1[0] + e1[1] + e1[2] + e1[3];
      const s4 ea0 = {bf16c(e0[0]), bf16c(e0[1]), bf16c(e0[2]), bf16c(e0[3])};
      const s4 ea1 = {bf16c(e1[0]), bf16c(e1[1]), bf16c(e1[2]), bf16c(e1[3])};
      const s4 vb0 = {bf16c(acc[2][0]), bf16c(acc[2][1]), bf16c(acc[2][2]),
                      bf16c(acc[2][3])};
      const s4 vb1 = {bf16c(acc[3][0]), bf16c(acc[3][1]), bf16c(acc[3][2]),
                      bf16c(acc[3][3])};
      ctxacc[0][0] = bmm16(ea0, vb0, ctxacc[0][0]);
      ctxacc[0][1] = bmm16(ea0, vb1, ctxacc[0][1]);
      ctxacc[1][0] = bmm16(ea1, vb0, ctxacc[1][0]);
      ctxacc[1][1] = bmm16(ea1, vb1, ctxacc[1][1]);
    }
  };

  aload(0);
  awrite(0);
  __syncthreads();
  for (int tl = 0; tl < 16; ++tl) {
    if (tl < 15) aload(tl + 1);
    compute(tl & 1);
    if (tl < 15) awrite((tl + 1) & 1);
    __syncthreads();
  }

  // ctx partials (fp32): lane holds ctx[d = a*16 + 4g + r][e = e2*16 + (lane&15)]
  {
    const size_t base = (size_t)((b * 4 + h) * 16 + chunk) * 1024;
    const int g4 = (lane >> 4) * 4, cc = lane & 15;
#pragma unroll
    for (int a = 0; a < 2; ++a)
#pragma unroll
      for (int e2 = 0; e2 < 2; ++e2)
#pragma unroll
        for (int r = 0; r < 4; ++r)
          cp[base + (size_t)(a * 16 + g4 + r) * 32 + e2 * 16 + cc] =
              ctxacc[a][e2][r];
  }
  // z partials: reduce across the 4 lane-groups sharing d = lane&15
#pragma unroll
  for (int s = 0; s < 2; ++s) {
    float z = zloc[s];
    z += __shfl_xor(z, 16);
    z += __shfl_xor(z, 32);
    if (lane < 16)
      zp[((b * 4 + h) * 16 + chunk) * 32 + s * 16 + lane] = z;
  }
}

// ---------------------------------------------------------------------------
// Kernel B: reduce chunk partials, normalize, fold
// P_b = SCALE * (W_out · ctx_b) · W_q. Verbatim round-2 (verified) structure;
// only change: P stored as bf16. Grid (16 b).
// ---------------------------------------------------------------------------
__global__ __launch_bounds__(256, 1) void makeP(
    const float* __restrict__ cp, const float* __restrict__ zp,
    const float* __restrict__ wout, const float* __restrict__ wqkv,
    unsigned short* __restrict__ Phi)
{
  const int b = blockIdx.x, t = threadIdx.x;
  __shared__ float ctxn[4096];
  __shared__ float zs[128];
  __shared__ float M[128][128];

  if (t < 128) {
    float s = 0.f;
    for (int ch = 0; ch < 16; ++ch)
      s += zp[((size_t)(b * 4 + (t >> 5)) * 16 + ch) * 32 + (t & 31)];
    zs[t] = s;
  }
  __syncthreads();
  for (int i = t; i < 4096; i += 256) {
    const int hh = i >> 10;
    float s = 0.f;
    for (int ch = 0; ch < 16; ++ch)
      s += cp[((size_t)((b * 4 + hh) * 16 + ch)) * 1024 + (i & 1023)];
    ctxn[i] = s / zs[i >> 5];
  }
  __syncthreads();
  {
    const int o = t >> 1;
    for (int j = 0; j < 64; ++j) {
      const int hd = (t & 1) * 64 + j;
      float s = 0.f;
#pragma unroll 8
      for (int e = 0; e < 32; ++e)
        s += wout[o * 128 + (hd >> 5) * 32 + e] * ctxn[(hd << 5) + e];
      M[o][hd] = s;
    }
  }
  __syncthreads();
  {
    const int o = t >> 1;
    for (int j = 0; j < 64; ++j) {
      const int c = (t & 1) * 64 + j;
      float s = 0.f;
#pragma unroll 8
      for (int hd = 0; hd < 128; ++hd) s += M[o][hd] * wqkv[hd * 128 + c];
      Phi[((size_t)b * 128 + o) * 128 + c] = (unsigned short)bf16c(s * SCALE);
    }
  }
}

// ---------------------------------------------------------------------------
// Kernel C: y[b] = P_b · x[b] + bias as D = x^T · P^T (MFMA, HBM-bound).
// Grid (128 chunks of 128 n, 16 b); 4 waves split the 128 output channels.
// ---------------------------------------------------------------------------
__global__ __launch_bounds__(256) void out_gemm(
    const float* __restrict__ x, const unsigned short* __restrict__ Phi,
    const float* __restrict__ bias, float* __restrict__ y)
{
  const int nb = blockIdx.x, b = blockIdx.y;
  const int tid = threadIdx.x, lane = tid & 63, w = tid >> 6;
  __shared__ __align__(16) char lds[128 * XSTRIDE];  // 35840 B

  // P B-frags (bf16, 16B-aligned): wave w owns o-tiles 2w, 2w+1.
  s8 pf[2][4];
#pragma unroll
  for (int ot2 = 0; ot2 < 2; ++ot2) {
    const int orow = (w * 2 + ot2) * 16 + (lane & 15);
#pragma unroll
    for (int kc = 0; kc < 4; ++kc)
      pf[ot2][kc] = *(const s8*)(Phi + ((size_t)b * 128 + orow) * 128 +
                                 kc * 32 + (lane >> 4) * 8);
  }

  // Stage x^T tile [128n][128c] via in-register 4x4 transpose.
  const float* xb = x + (size_t)b * 128 * 16384 + (size_t)nb * 128;
  {
    const int nq = tid & 31, ch = tid >> 5;
#pragma unroll
    for (int q = 0; q < 4; ++q) {
      const int c0 = ch * 4 + q * 32;
      f4 v[4];
#pragma unroll
      for (int i = 0; i < 4; ++i)
        v[i] = *(const f4*)(xb + (size_t)(c0 + i) * 16384 + nq * 4);
#pragma unroll
      for (int j = 0; j < 4; ++j) {
        s4 t = {bf16c(v[0][j]), bf16c(v[1][j]), bf16c(v[2][j]), bf16c(v[3][j])};
        *(s4*)(lds + (nq * 4 + j) * XSTRIDE + c0 * 2) = t;
      }
    }
  }
  __syncthreads();

  f4 acc[8][2];
#pragma unroll
  for (int nt = 0; nt < 8; ++nt)
#pragma unroll
    for (int ot2 = 0; ot2 < 2; ++ot2) acc[nt][ot2] = (f4){0.f, 0.f, 0.f, 0.f};

#pragma unroll
  for (int nt = 0; nt < 8; ++nt) {
    const char* rp = lds + (nt * 16 + (lane & 15)) * XSTRIDE + (lane >> 4) * 16;
    s8 af[4];
#pragma unroll
    for (int kc = 0; kc < 4; ++kc) {
      const s4 lo = *(const s4*)(rp + kc * 64);
      const s4 hi = *(const s4*)(rp + kc * 64 + 8);
      af[kc] = __builtin_shufflevector(lo, hi, 0, 1, 2, 3, 4, 5, 6, 7);
    }
#pragma unroll
    for (int kc = 0; kc < 4; ++kc)
#pragma unroll
      for (int ot2 = 0; ot2 < 2; ++ot2)
        acc[nt][ot2] = mfma32(af[kc], pf[ot2][kc], acc[nt][ot2]);
  }

  // Store: lane holds 4 consecutive n (regs) at o = ot*16 + (lane&15).
  const int g4 = (lane >> 4) * 4;
#pragma unroll
  for (int ot2 = 0; ot2 < 2; ++ot2) {
    const int o = (w * 2 + ot2) * 16 + (lane & 15);
    const float bv = bias[o];
    float* yo = y + ((size_t)b * 128 + o) * 16384 + (size_t)nb * 128;
#pragma unroll
    for (int nt = 0; nt < 8; ++nt) {
      f4 o4 = acc[nt][ot2];
      o4[0] += bv; o4[1] += bv; o4[2] += bv; o4[3] += bv;
      *(f4*)(yo + nt * 16 + g4) = o4;
    }
  }
}

extern "C" void kernel_launch(void* const* d_in, const int* in_sizes, int n_in,
                              void* d_out, int out_size, void* d_ws, size_t ws_size,
                              hipStream_t stream) {
  const float* x = (const float*)d_in[0];
  const float* wqkv = (const float*)d_in[1];
  const float* wout = (const float*)d_in[2];
  const float* bias = (const float*)d_in[3];
  float* cp = (float*)d_ws;                         // [16][4][16][1024] f32
  float* zp = cp + 1048576;                         // [16][4][16][32]  f32
  unsigned short* Phi = (unsigned short*)(cp + 1081344);  // [16][128][128] bf16
  float* y = (float*)d_out;

  ctx_kernel<<<dim3(16, 16), 256, 0, stream>>>(x, wqkv, cp, zp);
  makeP<<<dim3(16), 256, 0, stream>>>(cp, zp, wout, wqkv, Phi);
  out_gemm<<<dim3(128, 16), 256, 0, stream>>>(x, Phi, bias, y);
}

// Round 5
// 108.073 us; speedup vs baseline: 6.4865x; 3.4972x over previous
//
#include <hip/hip_runtime.h>

typedef float f4 __attribute__((ext_vector_type(4)));
typedef short s4 __attribute__((ext_vector_type(4)));
typedef short s8 __attribute__((ext_vector_type(8)));
typedef unsigned int u32;

#define SCALE 0.17677669529663687f

static __device__ __forceinline__ short bf16c(float f) {
  u32 u = __builtin_bit_cast(u32, f);
  u32 r = u + 0x7fffu + ((u >> 16) & 1u);
  return (short)(r >> 16);
}

static __device__ __forceinline__ f4 mfma32(s8 a, s8 b, f4 c) {
  return __builtin_amdgcn_mfma_f32_16x16x32_bf16(a, b, c, 0, 0, 0);
}
// Zero-padded effective K=16. Slots j=0..3 of A pair with slots j=0..3 of B:
// both operands use the m92-verified contiguous mapping k=(l>>4)*8+j, so
// slot j of A and slot j of B contract at the same k.
static __device__ __forceinline__ f4 bmm16(s4 a, s4 b, f4 c) {
  s8 A = {a[0], a[1], a[2], a[3], (short)0, (short)0, (short)0, (short)0};
  s8 B = {b[0], b[1], b[2], b[3], (short)0, (short)0, (short)0, (short)0};
  return __builtin_amdgcn_mfma_f32_16x16x32_bf16(A, B, c, 0, 0, 0);
}

#define XSTRIDE 280  // bytes per x^T row in LDS: 128 bf16 = 256B + 24B pad

// ---------------------------------------------------------------------------
// Kernel A: fused KV 1x1-conv (MFMA) + exp + ctx accumulation.  (unchanged)
// ---------------------------------------------------------------------------
__global__ __launch_bounds__(256) void ctx_kernel(
    const float* __restrict__ x, const float* __restrict__ wqkv,
    float* __restrict__ cp, float* __restrict__ zp)
{
  const int chunk = blockIdx.x, b = blockIdx.y;
  const int tid = threadIdx.x, lane = tid & 63, h = tid >> 6;
  __shared__ __align__(16) char lds[2 * 64 * XSTRIDE];  // 35840 B

  s8 wf[4][4];
  {
    const int colr = lane & 15, g = lane >> 4;
#pragma unroll
    for (int s = 0; s < 4; ++s) {
      const int grow = (s < 2 ? 128 : 256) + h * 32 + (s & 1) * 16 + colr;
#pragma unroll
      for (int kc = 0; kc < 4; ++kc) {
        const float* src = wqkv + grow * 128 + kc * 32 + g * 8;
        const f4 a = *(const f4*)src;
        const f4 c2 = *(const f4*)(src + 4);
        s8 t = {bf16c(a[0]), bf16c(a[1]), bf16c(a[2]), bf16c(a[3]),
                bf16c(c2[0]), bf16c(c2[1]), bf16c(c2[2]), bf16c(c2[3])};
        wf[s][kc] = t;
      }
    }
  }

  f4 ctxacc[2][2];
#pragma unroll
  for (int a = 0; a < 2; ++a)
#pragma unroll
    for (int e2 = 0; e2 < 2; ++e2) ctxacc[a][e2] = (f4){0.f, 0.f, 0.f, 0.f};
  float zloc[2] = {0.f, 0.f};

  const float* xb = x + (size_t)b * 128 * 16384 + chunk * 1024;
  const int nq = tid & 15, ch = tid >> 4;
  f4 v[2][4];

  auto aload = [&](int tl) {
#pragma unroll
    for (int q = 0; q < 2; ++q) {
      const int c0 = ch * 4 + q * 64;
#pragma unroll
      for (int i = 0; i < 4; ++i)
        v[q][i] = *(const f4*)(xb + (size_t)(c0 + i) * 16384 + tl * 64 + nq * 4);
    }
  };
  auto awrite = [&](int buf) {
#pragma unroll
    for (int q = 0; q < 2; ++q) {
      const int c0 = ch * 4 + q * 64;
#pragma unroll
      for (int j = 0; j < 4; ++j) {
        s4 t = {bf16c(v[q][0][j]), bf16c(v[q][1][j]), bf16c(v[q][2][j]),
                bf16c(v[q][3][j])};
        *(s4*)(lds + buf * (64 * XSTRIDE) + (nq * 4 + j) * XSTRIDE + c0 * 2) = t;
      }
    }
  };
  auto compute = [&](int buf) {
#pragma unroll
    for (int nt = 0; nt < 4; ++nt) {
      const char* rp =
          lds + buf * (64 * XSTRIDE) + (nt * 16 + (lane & 15)) * XSTRIDE +
          (lane >> 4) * 16;
      s8 af[4];
#pragma unroll
      for (int kc = 0; kc < 4; ++kc) {
        const s4 lo = *(const s4*)(rp + kc * 64);
        const s4 hi = *(const s4*)(rp + kc * 64 + 8);
        af[kc] = __builtin_shufflevector(lo, hi, 0, 1, 2, 3, 4, 5, 6, 7);
      }
      f4 acc[4];
#pragma unroll
      for (int s = 0; s < 4; ++s) acc[s] = (f4){0.f, 0.f, 0.f, 0.f};
#pragma unroll
      for (int kc = 0; kc < 4; ++kc)
#pragma unroll
        for (int s = 0; s < 4; ++s)
          acc[s] = mfma32(af[kc], wf[s][kc], acc[s]);
      f4 e0, e1;
#pragma unroll
      for (int r = 0; r < 4; ++r) {
        e0[r] = __expf(acc[0][r]);
        e1[r] = __expf(acc[1][r]);
      }
      zloc[0] += e0[0] + e0[1] + e0[2] + e0[3];
      zloc[1] += e1[0] + e1[1] + e1[2] + e1[3];
      const s4 ea0 = {bf16c(e0[0]), bf16c(e0[1]), bf16c(e0[2]), bf16c(e0[3])};
      const s4 ea1 = {bf16c(e1[0]), bf16c(e1[1]), bf16c(e1[2]), bf16c(e1[3])};
      const s4 vb0 = {bf16c(acc[2][0]), bf16c(acc[2][1]), bf16c(acc[2][2]),
                      bf16c(acc[2][3])};
      const s4 vb1 = {bf16c(acc[3][0]), bf16c(acc[3][1]), bf16c(acc[3][2]),
                      bf16c(acc[3][3])};
      ctxacc[0][0] = bmm16(ea0, vb0, ctxacc[0][0]);
      ctxacc[0][1] = bmm16(ea0, vb1, ctxacc[0][1]);
      ctxacc[1][0] = bmm16(ea1, vb0, ctxacc[1][0]);
      ctxacc[1][1] = bmm16(ea1, vb1, ctxacc[1][1]);
    }
  };

  aload(0);
  awrite(0);
  __syncthreads();
  for (int tl = 0; tl < 16; ++tl) {
    if (tl < 15) aload(tl + 1);
    compute(tl & 1);
    if (tl < 15) awrite((tl + 1) & 1);
    __syncthreads();
  }

  {
    const size_t base = (size_t)((b * 4 + h) * 16 + chunk) * 1024;
    const int g4 = (lane >> 4) * 4, cc = lane & 15;
#pragma unroll
    for (int a = 0; a < 2; ++a)
#pragma unroll
      for (int e2 = 0; e2 < 2; ++e2)
#pragma unroll
        for (int r = 0; r < 4; ++r)
          cp[base + (size_t)(a * 16 + g4 + r) * 32 + e2 * 16 + cc] =
              ctxacc[a][e2][r];
  }
#pragma unroll
  for (int s = 0; s < 2; ++s) {
    float z = zloc[s];
    z += __shfl_xor(z, 16);
    z += __shfl_xor(z, 32);
    if (lane < 16)
      zp[((b * 4 + h) * 16 + chunk) * 32 + s * 16 + lane] = z;
  }
}

// ---------------------------------------------------------------------------
// Kernel B (rewritten): grid (8 row-groups x 16 b), 256 threads.
// Each block: f4 reduction of partials -> normalized ctxn in LDS, its own
// 16-row M slab, its own 16-row P slab -> Phi bf16. No serial 64-loops, no
// scalar global reads; per-thread ~1.3K f4 ops.
// ---------------------------------------------------------------------------
__global__ __launch_bounds__(256, 2) void makeP(
    const float* __restrict__ cp, const float* __restrict__ zp,
    const float* __restrict__ wout, const float* __restrict__ wqkv,
    unsigned short* __restrict__ Phi)
{
  const int rg = blockIdx.x, b = blockIdx.y, t = threadIdx.x;
  __shared__ float ctxn[4096];    // [hd][e], normalized
  __shared__ float zs[128];
  __shared__ float Ms[16][129];   // M slab, padded

  if (t < 128) {
    float s = 0.f;
#pragma unroll
    for (int ch = 0; ch < 16; ++ch)
      s += zp[((size_t)(b * 4 + (t >> 5)) * 16 + ch) * 32 + (t & 31)];
    zs[t] = s;
  }
  __syncthreads();
  {
    // thread t -> 16 consecutive entries [t*16, t*16+16); all share one hd
    const int i0 = t * 16;
    const int hh = i0 >> 10;
    f4 s0 = {0.f,0.f,0.f,0.f}, s1 = s0, s2 = s0, s3 = s0;
    const float* src = cp + ((size_t)(b * 4 + hh) * 16) * 1024 + (i0 & 1023);
#pragma unroll
    for (int ch = 0; ch < 16; ++ch) {
      const float* p = src + ch * 1024;
      s0 += *(const f4*)(p);
      s1 += *(const f4*)(p + 4);
      s2 += *(const f4*)(p + 8);
      s3 += *(const f4*)(p + 12);
    }
    const float zinv = 1.f / zs[i0 >> 5];
    *(f4*)(ctxn + i0)      = s0 * zinv;
    *(f4*)(ctxn + i0 + 4)  = s1 * zinv;
    *(f4*)(ctxn + i0 + 8)  = s2 * zinv;
    *(f4*)(ctxn + i0 + 12) = s3 * zinv;
  }
  __syncthreads();
  {
    // M[o][hd] = sum_e wout[rg*16+o][h(hd)*32+e] * ctxn[hd*32+e]
    // thread t -> o = t>>4, hd in [(t&15)*8, +8)  (h constant within the 8)
    const int o = t >> 4, hd0 = (t & 15) * 8;
    const int hh = hd0 >> 5;
    f4 wseg[8];
    const float* wp = wout + (size_t)(rg * 16 + o) * 128 + hh * 32;
#pragma unroll
    for (int i = 0; i < 8; ++i) wseg[i] = *(const f4*)(wp + i * 4);
#pragma unroll
    for (int j = 0; j < 8; ++j) {
      const float* cn = ctxn + (hd0 + j) * 32;
      f4 acc = {0.f, 0.f, 0.f, 0.f};
#pragma unroll
      for (int i = 0; i < 8; ++i) acc += wseg[i] * *(const f4*)(cn + i * 4);
      Ms[o][hd0 + j] = acc[0] + acc[1] + acc[2] + acc[3];
    }
  }
  __syncthreads();
  {
    // P[o][c] = SCALE * sum_hd Ms[o][hd] * wqkv[hd*128+c]
    // thread t -> o = t>>4, c in [(t&15)*8, +8)
    const int o = t >> 4, c0 = (t & 15) * 8;
    f4 a0 = {0.f,0.f,0.f,0.f}, a1 = a0;
#pragma unroll 8
    for (int hd = 0; hd < 128; ++hd) {
      const float m = Ms[o][hd];
      const float* wp = wqkv + (size_t)hd * 128 + c0;
      a0 += m * *(const f4*)(wp);
      a1 += m * *(const f4*)(wp + 4);
    }
    a0 *= SCALE;
    a1 *= SCALE;
    s8 out = {bf16c(a0[0]), bf16c(a0[1]), bf16c(a0[2]), bf16c(a0[3]),
              bf16c(a1[0]), bf16c(a1[1]), bf16c(a1[2]), bf16c(a1[3])};
    *(s8*)(Phi + ((size_t)b * 128 + rg * 16 + o) * 128 + c0) = out;
  }
}

// ---------------------------------------------------------------------------
// Kernel C: y[b] = P_b · x[b] + bias as D = x^T · P^T.  (unchanged)
// ---------------------------------------------------------------------------
__global__ __launch_bounds__(256) void out_gemm(
    const float* __restrict__ x, const unsigned short* __restrict__ Phi,
    const float* __restrict__ bias, float* __restrict__ y)
{
  const int nb = blockIdx.x, b = blockIdx.y;
  const int tid = threadIdx.x, lane = tid & 63, w = tid >> 6;
  __shared__ __align__(16) char lds[128 * XSTRIDE];  // 35840 B

  s8 pf[2][4];
#pragma unroll
  for (int ot2 = 0; ot2 < 2; ++ot2) {
    const int orow = (w * 2 + ot2) * 16 + (lane & 15);
#pragma unroll
    for (int kc = 0; kc < 4; ++kc)
      pf[ot2][kc] = *(const s8*)(Phi + ((size_t)b * 128 + orow) * 128 +
                                 kc * 32 + (lane >> 4) * 8);
  }

  const float* xb = x + (size_t)b * 128 * 16384 + (size_t)nb * 128;
  {
    const int nq = tid & 31, ch = tid >> 5;
#pragma unroll
    for (int q = 0; q < 4; ++q) {
      const int c0 = ch * 4 + q * 32;
      f4 v[4];
#pragma unroll
      for (int i = 0; i < 4; ++i)
        v[i] = *(const f4*)(xb + (size_t)(c0 + i) * 16384 + nq * 4);
#pragma unroll
      for (int j = 0; j < 4; ++j) {
        s4 t = {bf16c(v[0][j]), bf16c(v[1][j]), bf16c(v[2][j]), bf16c(v[3][j])};
        *(s4*)(lds + (nq * 4 + j) * XSTRIDE + c0 * 2) = t;
      }
    }
  }
  __syncthreads();

  f4 acc[8][2];
#pragma unroll
  for (int nt = 0; nt < 8; ++nt)
#pragma unroll
    for (int ot2 = 0; ot2 < 2; ++ot2) acc[nt][ot2] = (f4){0.f, 0.f, 0.f, 0.f};

#pragma unroll
  for (int nt = 0; nt < 8; ++nt) {
    const char* rp = lds + (nt * 16 + (lane & 15)) * XSTRIDE + (lane >> 4) * 16;
    s8 af[4];
#pragma unroll
    for (int kc = 0; kc < 4; ++kc) {
      const s4 lo = *(const s4*)(rp + kc * 64);
      const s4 hi = *(const s4*)(rp + kc * 64 + 8);
      af[kc] = __builtin_shufflevector(lo, hi, 0, 1, 2, 3, 4, 5, 6, 7);
    }
#pragma unroll
    for (int kc = 0; kc < 4; ++kc)
#pragma unroll
      for (int ot2 = 0; ot2 < 2; ++ot2)
        acc[nt][ot2] = mfma32(af[kc], pf[ot2][kc], acc[nt][ot2]);
  }

  const int g4 = (lane >> 4) * 4;
#pragma unroll
  for (int ot2 = 0; ot2 < 2; ++ot2) {
    const int o = (w * 2 + ot2) * 16 + (lane & 15);
    const float bv = bias[o];
    float* yo = y + ((size_t)b * 128 + o) * 16384 + (size_t)nb * 128;
#pragma unroll
    for (int nt = 0; nt < 8; ++nt) {
      f4 o4 = acc[nt][ot2];
      o4[0] += bv; o4[1] += bv; o4[2] += bv; o4[3] += bv;
      *(f4*)(yo + nt * 16 + g4) = o4;
    }
  }
}

extern "C" void kernel_launch(void* const* d_in, const int* in_sizes, int n_in,
                              void* d_out, int out_size, void* d_ws, size_t ws_size,
                              hipStream_t stream) {
  const float* x = (const float*)d_in[0];
  const float* wqkv = (const float*)d_in[1];
  const float* wout = (const float*)d_in[2];
  const float* bias = (const float*)d_in[3];
  float* cp = (float*)d_ws;                         // [16][4][16][1024] f32
  float* zp = cp + 1048576;                         // [16][4][16][32]  f32
  unsigned short* Phi = (unsigned short*)(cp + 1081344);  // [16][128][128] bf16
  float* y = (float*)d_out;

  ctx_kernel<<<dim3(16, 16), 256, 0, stream>>>(x, wqkv, cp, zp);
  makeP<<<dim3(8, 16), 256, 0, stream>>>(cp, zp, wout, wqkv, Phi);
  out_gemm<<<dim3(128, 16), 256, 0, stream>>>(x, Phi, bias, y);
}